// Round 2
// baseline (8083.117 us; speedup 1.0000x reference)
//
#include <hip/hip_runtime.h>

#define N_NODES 20000
#define N_EDGES 320000
#define NPAD    20032
#define BN_EPS  1e-5f

using bf16x8 = __attribute__((ext_vector_type(8))) short;
using f32x4  = __attribute__((ext_vector_type(4))) float;

__device__ __forceinline__ ushort f2bf(float f) {
  unsigned x = __float_as_uint(f);
  return (ushort)((x + 0x7fffu + ((x >> 16) & 1u)) >> 16);   // RNE
}

// ---------- degree ----------
__global__ void k_count(const int* __restrict__ dst, float* __restrict__ cnt) {
  int t = blockIdx.x * blockDim.x + threadIdx.x;
  if (t < N_EDGES) { unsigned d = (unsigned)dst[t]; if (d < N_NODES) atomicAdd(&cnt[d], 1.0f); }
}
__global__ void k_inv(const float* __restrict__ cnt, float* __restrict__ inv) {
  int t = blockIdx.x * blockDim.x + threadIdx.x;
  if (t < N_NODES) inv[t] = 1.0f / fmaxf(cnt[t], 1.0f);
}

// ---------- convert all weight matrices to one bf16 pool ----------
// segments (elements): enc 16384 | Wl0 32768 | Wr0 32768 | Wl1 65536 | Wr1 65536
//                      | Wl2 65536 | Wr2 65536 | Wl3 32768 | Wr3 32768 | dec 16384
__global__ void k_cvtw(const float* s0, const float* s1, const float* s2,
                       const float* s3, const float* s4, const float* s5,
                       const float* s6, const float* s7, const float* s8,
                       const float* s9, ushort* __restrict__ dst) {
  int t = blockIdx.x * blockDim.x + threadIdx.x;
  int e = t * 4;
  if (e >= 425984) return;
  const float* s; int off;
  if      (e < 16384)  { s = s0; off = e; }
  else if (e < 49152)  { s = s1; off = e - 16384; }
  else if (e < 81920)  { s = s2; off = e - 49152; }
  else if (e < 147456) { s = s3; off = e - 81920; }
  else if (e < 212992) { s = s4; off = e - 147456; }
  else if (e < 278528) { s = s5; off = e - 212992; }
  else if (e < 344064) { s = s6; off = e - 278528; }
  else if (e < 376832) { s = s7; off = e - 344064; }
  else if (e < 409600) { s = s8; off = e - 376832; }
  else                 { s = s9; off = e - 409600; }
  float4 v = *(const float4*)(s + off);
  dst[e + 0] = f2bf(v.x); dst[e + 1] = f2bf(v.y);
  dst[e + 2] = f2bf(v.z); dst[e + 3] = f2bf(v.w);
}

// ---------- scatter add: agg[dst] += z[src] (fp32), 8 elems/thread ----------
__global__ void k_scatter(const float* __restrict__ z, const int* __restrict__ src,
                          const int* __restrict__ dst, float* __restrict__ agg, int gl) {
  int t = blockIdx.x * blockDim.x + threadIdx.x;
  int e = t >> gl;
  if (e >= N_EDGES) return;
  int g = t & ((1 << gl) - 1);
  int dim = 8 << gl;
  unsigned s = (unsigned)src[e], d = (unsigned)dst[e];
  if (s >= N_NODES || d >= N_NODES) return;
  const float* zp = z + (size_t)s * dim + g * 8;
  float4 a = *(const float4*)zp, b = *(const float4*)(zp + 4);
  float* ap = agg + (size_t)d * dim + g * 8;
  atomicAdd(ap + 0, a.x); atomicAdd(ap + 1, a.y); atomicAdd(ap + 2, a.z); atomicAdd(ap + 3, a.w);
  atomicAdd(ap + 4, b.x); atomicAdd(ap + 5, b.y); atomicAdd(ap + 6, b.z); atomicAdd(ap + 7, b.w);
}

// ---------- dual GEMM: C = (A1*rsc)@W1^T (+ A2@W2^T) + bias; f32 in, bf16 MFMA, f32 out
// A row-major [*][din] f32; W bf16 [dout][din]; block 64(M)x64(N), 4 waves.
__global__ __launch_bounds__(256) void k_gemm(
    const float* __restrict__ A1, const float* __restrict__ rsc,
    const ushort* __restrict__ W1, const float* __restrict__ A2,
    const ushort* __restrict__ W2, const float* __restrict__ bias,
    float* __restrict__ C, int Mstore, int din, int dout)
{
  int lane = threadIdx.x & 63, wid = threadIdx.x >> 6;
  int la = lane & 15, lb = lane >> 4;
  int rowBase = blockIdx.x * 64 + wid * 16;
  int colBase = blockIdx.y * 64;
  int arow = rowBase + la; if (arow >= N_NODES) arow = N_NODES - 1;
  float s1 = rsc ? rsc[arow] : 1.0f;

  f32x4 acc[4] = {{0,0,0,0},{0,0,0,0},{0,0,0,0},{0,0,0,0}};

  const float* A = A1; const ushort* W = W1; float sc = s1;
  #pragma unroll 1
  for (int pass = 0; pass < 2; ++pass) {
    const float* ap = A + (size_t)arow * din + lb * 8;
    for (int k0 = 0; k0 < din; k0 += 32) {
      float4 u = *(const float4*)(ap + k0);
      float4 v = *(const float4*)(ap + k0 + 4);
      bf16x8 a;
      a[0] = (short)f2bf(u.x * sc); a[1] = (short)f2bf(u.y * sc);
      a[2] = (short)f2bf(u.z * sc); a[3] = (short)f2bf(u.w * sc);
      a[4] = (short)f2bf(v.x * sc); a[5] = (short)f2bf(v.y * sc);
      a[6] = (short)f2bf(v.z * sc); a[7] = (short)f2bf(v.w * sc);
      #pragma unroll
      for (int nf = 0; nf < 4; ++nf) {
        bf16x8 b = *(const bf16x8*)(W + (size_t)(colBase + nf * 16 + la) * din + k0 + lb * 8);
        acc[nf] = __builtin_amdgcn_mfma_f32_16x16x32_bf16(a, b, acc[nf], 0, 0, 0);
      }
    }
    if (!A2) break;
    A = A2; W = W2; sc = 1.0f;
  }

  // C/D layout: col = lane&15, row = (lane>>4)*4 + reg
  #pragma unroll
  for (int nf = 0; nf < 4; ++nf) {
    int col = colBase + nf * 16 + la;
    float bv = bias ? bias[col] : 0.0f;
    #pragma unroll
    for (int i = 0; i < 4; ++i) {
      int row = rowBase + lb * 4 + i;
      if (row < Mstore) C[(size_t)row * dout + col] = acc[nf][i] + bv;
    }
  }
}

// ---------- BN stats (dim 256): stats[c]=sum, stats[256+c]=sumsq ----------
__global__ void k_stats(const float* __restrict__ h, float* __restrict__ stats,
                        int rowsPerBlock) {
  int c = threadIdx.x;
  int r0 = blockIdx.x * rowsPerBlock;
  int r1 = r0 + rowsPerBlock; if (r1 > N_NODES) r1 = N_NODES;
  float s = 0.f, q = 0.f;
  for (int r = r0; r < r1; ++r) {
    float v = h[(size_t)r * 256 + c];
    s += v; q += v * v;
  }
  atomicAdd(&stats[c], s);
  atomicAdd(&stats[256 + c], q);
}

// ---------- per-column scale/shift ----------
__global__ void k_bnprep(const float* __restrict__ stats, const float* __restrict__ gamma,
                         const float* __restrict__ beta, float* __restrict__ bnp) {
  int c = threadIdx.x;
  float m = stats[c] * (1.0f / N_NODES);
  float var = stats[256 + c] * (1.0f / N_NODES) - m * m;
  float rs = rsqrtf(var + BN_EPS);
  float sc = rs * gamma[c];
  bnp[c] = sc;
  bnp[256 + c] = beta[c] - m * sc;
}

// ---------- BN apply + ReLU in place (dim 256), 4 elems/thread ----------
__global__ void k_bnrelu(float* __restrict__ h, const float* __restrict__ bnp) {
  int t = blockIdx.x * blockDim.x + threadIdx.x;
  int i = t >> 6;
  if (i >= N_NODES) return;
  int c4 = (t & 63) * 4;
  float4* p = (float4*)(h + (size_t)i * 256 + c4);
  float4 v = *p;
  float o0 = fmaxf(v.x * bnp[c4 + 0] + bnp[256 + c4 + 0], 0.f);
  float o1 = fmaxf(v.y * bnp[c4 + 1] + bnp[256 + c4 + 1], 0.f);
  float o2 = fmaxf(v.z * bnp[c4 + 2] + bnp[256 + c4 + 2], 0.f);
  float o3 = fmaxf(v.w * bnp[c4 + 3] + bnp[256 + c4 + 3], 0.f);
  *p = make_float4(o0, o1, o2, o3);
}

extern "C" void kernel_launch(void* const* d_in, const int* in_sizes, int n_in,
                              void* d_out, int out_size, void* d_ws, size_t ws_size,
                              hipStream_t stream) {
  const float* x    = (const float*)d_in[0];
  const int*   ei   = (const int*)d_in[1];
  const float* encW = (const float*)d_in[2];
  const float* encb = (const float*)d_in[3];
  const float* Wl0  = (const float*)d_in[4];
  const float* bl0  = (const float*)d_in[5];
  const float* Wr0  = (const float*)d_in[6];
  const float* Wl1  = (const float*)d_in[7];
  const float* bl1  = (const float*)d_in[8];
  const float* Wr1  = (const float*)d_in[9];
  const float* Wl2  = (const float*)d_in[10];
  const float* bl2  = (const float*)d_in[11];
  const float* Wr2  = (const float*)d_in[12];
  const float* Wl3  = (const float*)d_in[13];
  const float* bl3  = (const float*)d_in[14];
  const float* Wr3  = (const float*)d_in[15];
  const float* g0   = (const float*)d_in[16];
  const float* b0   = (const float*)d_in[17];
  const float* g1   = (const float*)d_in[18];
  const float* b1   = (const float*)d_in[19];
  const float* g2   = (const float*)d_in[20];
  const float* b2   = (const float*)d_in[21];
  const float* decW = (const float*)d_in[22];
  const float* decb = (const float*)d_in[23];

  const int* src = ei;
  const int* dst = ei + N_EDGES;

  char* ws = (char*)d_ws;
  size_t off = 0;
  auto alloc = [&](size_t bytes) { char* p = ws + off; off += (bytes + 255) & ~255ull; return p; };
  float*  bufA  = (float*) alloc((size_t)NPAD * 256 * 4);
  float*  bufB  = (float*) alloc((size_t)NPAD * 256 * 4);
  float*  agg   = (float*) alloc((size_t)NPAD * 256 * 4);
  float*  cnt   = (float*) alloc((size_t)N_NODES * 4);
  float*  inv   = (float*) alloc((size_t)N_NODES * 4);
  float*  stats = (float*) alloc(512 * 4);
  float*  bnp   = (float*) alloc(512 * 4);
  ushort* wpool = (ushort*)alloc(425984 * 2);

  const ushort* wEnc = wpool;
  const ushort* wL0  = wpool + 16384;
  const ushort* wR0  = wpool + 49152;
  const ushort* wL1  = wpool + 81920;
  const ushort* wR1  = wpool + 147456;
  const ushort* wL2  = wpool + 212992;
  const ushort* wR2  = wpool + 278528;
  const ushort* wL3  = wpool + 344064;
  const ushort* wR3  = wpool + 376832;
  const ushort* wDec = wpool + 409600;

  hipMemsetAsync(cnt, 0, (size_t)N_NODES * 4, stream);
  k_count<<<(N_EDGES + 255) / 256, 256, 0, stream>>>(dst, cnt);
  k_inv<<<(N_NODES + 255) / 256, 256, 0, stream>>>(cnt, inv);
  k_cvtw<<<(106496 + 255) / 256, 256, 0, stream>>>(encW, Wl0, Wr0, Wl1, Wr1, Wl2, Wr2,
                                                   Wl3, Wr3, decW, wpool);

  // encoder: bufA = x @ encW^T + encb
  {
    dim3 grid(NPAD / 64, 2);
    k_gemm<<<grid, 256, 0, stream>>>(x, nullptr, wEnc, nullptr, nullptr, encb,
                                     bufA, N_NODES, 128, 128);
  }

  auto sage = [&](const float* z, int din_, const ushort* Wlb, const float* bl,
                  const ushort* Wrb, int dout_, float* outb) {
    int gl = (din_ == 256) ? 5 : 4;
    hipMemsetAsync(agg, 0, (size_t)N_NODES * din_ * 4, stream);
    int totalS = N_EDGES << gl;
    k_scatter<<<(totalS + 255) / 256, 256, 0, stream>>>(z, src, dst, agg, gl);
    dim3 grid(NPAD / 64, dout_ / 64);
    k_gemm<<<grid, 256, 0, stream>>>(agg, inv, Wlb, z, Wrb, bl,
                                     outb, N_NODES, din_, dout_);
  };
  auto bnrelu = [&](float* h, const float* ga, const float* be) {
    hipMemsetAsync(stats, 0, 512 * 4, stream);
    k_stats<<<100, 256, 0, stream>>>(h, stats, 200);
    k_bnprep<<<1, 256, 0, stream>>>(stats, ga, be, bnp);
    int total = N_NODES * 64;
    k_bnrelu<<<(total + 255) / 256, 256, 0, stream>>>(h, bnp);
  };

  sage(bufA, 128, wL0, bl0, wR0, 256, bufB); bnrelu(bufB, g0, b0);
  sage(bufB, 256, wL1, bl1, wR1, 256, bufA); bnrelu(bufA, g1, b1);
  sage(bufA, 256, wL2, bl2, wR2, 256, bufB); bnrelu(bufB, g2, b2);
  sage(bufB, 256, wL3, bl3, wR3, 128, bufA);   // layer 3: no BN/ReLU

  // decoder: d_out = bufA @ decW^T + decb
  {
    dim3 grid(NPAD / 64, 2);
    k_gemm<<<grid, 256, 0, stream>>>(bufA, nullptr, wDec, nullptr, nullptr, decb,
                                     (float*)d_out, N_NODES, 128, 128);
  }
}

// Round 3
// 663.453 us; speedup vs baseline: 12.1834x; 12.1834x over previous
//
#include <hip/hip_runtime.h>

#define N_NODES 20000
#define N_EDGES 320000
#define NPAD    20032
#define BN_EPS  1e-5f

using bf16x8 = __attribute__((ext_vector_type(8))) short;
using f32x4  = __attribute__((ext_vector_type(4))) float;

__device__ __forceinline__ ushort f2bf(float f) {
  unsigned x = __float_as_uint(f);
  return (ushort)((x + 0x7fffu + ((x >> 16) & 1u)) >> 16);   // RNE
}

// ---------- CSR build ----------
__global__ void k_deg(const int* __restrict__ dst, int* __restrict__ deg) {
  int t = blockIdx.x * blockDim.x + threadIdx.x;
  if (t < N_EDGES) { unsigned d = (unsigned)dst[t]; if (d < N_NODES) atomicAdd(&deg[d], 1); }
}

// single-block inclusive scan -> rowptr[0..N_NODES], plus inv[i]=1/max(deg,1)
__global__ void k_scan(const int* __restrict__ deg, int* __restrict__ rowptr,
                       float* __restrict__ inv) {
  __shared__ int buf[256];
  __shared__ int base;
  if (threadIdx.x == 0) { base = 0; rowptr[0] = 0; }
  __syncthreads();
  for (int c0 = 0; c0 < N_NODES; c0 += 256) {
    int i = c0 + threadIdx.x;
    int v = (i < N_NODES) ? deg[i] : 0;
    if (i < N_NODES) inv[i] = 1.0f / (float)max(v, 1);
    buf[threadIdx.x] = v;
    __syncthreads();
    #pragma unroll
    for (int s = 1; s < 256; s <<= 1) {
      int t = (threadIdx.x >= s) ? buf[threadIdx.x - s] : 0;
      __syncthreads();
      buf[threadIdx.x] += t;
      __syncthreads();
    }
    if (i < N_NODES) rowptr[i + 1] = base + buf[threadIdx.x];
    __syncthreads();
    if (threadIdx.x == 0) base += buf[255];
    __syncthreads();
  }
}

__global__ void k_fill(const int* __restrict__ src, const int* __restrict__ dst,
                       int* __restrict__ cursor, int* __restrict__ col) {
  int e = blockIdx.x * blockDim.x + threadIdx.x;
  if (e >= N_EDGES) return;
  unsigned d = (unsigned)dst[e];
  if (d >= N_NODES) return;
  int p = atomicAdd(&cursor[d], 1);
  col[p] = src[e];
}

// ---------- weights -> bf16 pool ----------
__global__ void k_cvtw(const float* s0, const float* s1, const float* s2,
                       const float* s3, const float* s4, const float* s5,
                       const float* s6, const float* s7, const float* s8,
                       const float* s9, ushort* __restrict__ dst) {
  int t = blockIdx.x * blockDim.x + threadIdx.x;
  int e = t * 4;
  if (e >= 425984) return;
  const float* s; int off;
  if      (e < 16384)  { s = s0; off = e; }
  else if (e < 49152)  { s = s1; off = e - 16384; }
  else if (e < 81920)  { s = s2; off = e - 49152; }
  else if (e < 147456) { s = s3; off = e - 81920; }
  else if (e < 212992) { s = s4; off = e - 147456; }
  else if (e < 278528) { s = s5; off = e - 212992; }
  else if (e < 344064) { s = s6; off = e - 278528; }
  else if (e < 376832) { s = s7; off = e - 344064; }
  else if (e < 409600) { s = s8; off = e - 376832; }
  else                 { s = s9; off = e - 409600; }
  float4 v = *(const float4*)(s + off);
  dst[e + 0] = f2bf(v.x); dst[e + 1] = f2bf(v.y);
  dst[e + 2] = f2bf(v.z); dst[e + 3] = f2bf(v.w);
}

// ---------- gather-mean: one wave per node, mean[i] = inv[i] * sum_{j} z[col[j]] ----------
template <int DIM>
__global__ __launch_bounds__(256) void k_gather(
    const float* __restrict__ z, const int* __restrict__ rowptr,
    const int* __restrict__ col, const float* __restrict__ inv,
    float* __restrict__ mean) {
  int node = blockIdx.x * 4 + (threadIdx.x >> 6);
  if (node >= N_NODES) return;
  int lane = threadIdx.x & 63;
  constexpr int V = DIM / 64;                      // 2 (din=128) or 4 (din=256)
  float acc[V] = {};
  int r0 = rowptr[node], r1 = rowptr[node + 1];
  for (int j = r0; j < r1; ++j) {
    int s = col[j];
    const float* zp = z + (size_t)s * DIM + lane * V;
    if constexpr (V == 4) {
      float4 v = *(const float4*)zp;
      acc[0] += v.x; acc[1] += v.y; acc[2] += v.z; acc[3] += v.w;
    } else {
      float2 v = *(const float2*)zp;
      acc[0] += v.x; acc[1] += v.y;
    }
  }
  float iv = inv[node];
  float* mp = mean + (size_t)node * DIM + lane * V;
  #pragma unroll
  for (int k = 0; k < V; ++k) mp[k] = acc[k] * iv;
}

// ---------- dual GEMM: C = A1@W1^T (+ A2@W2^T) + bias; f32 A, bf16 W, fp32 acc ----------
__global__ __launch_bounds__(256) void k_gemm(
    const float* __restrict__ A1, const ushort* __restrict__ W1,
    const float* __restrict__ A2, const ushort* __restrict__ W2,
    const float* __restrict__ bias, float* __restrict__ C,
    int Mstore, int din, int dout)
{
  int lane = threadIdx.x & 63, wid = threadIdx.x >> 6;
  int la = lane & 15, lb = lane >> 4;
  int rowBase = blockIdx.x * 64 + wid * 16;
  int colBase = blockIdx.y * 64;
  int arow = rowBase + la; if (arow >= N_NODES) arow = N_NODES - 1;

  f32x4 acc[4] = {{0,0,0,0},{0,0,0,0},{0,0,0,0},{0,0,0,0}};

  const float* A = A1; const ushort* W = W1;
  #pragma unroll 1
  for (int pass = 0; pass < 2; ++pass) {
    const float* ap = A + (size_t)arow * din + lb * 8;
    for (int k0 = 0; k0 < din; k0 += 32) {
      float4 u = *(const float4*)(ap + k0);
      float4 v = *(const float4*)(ap + k0 + 4);
      bf16x8 a;
      a[0] = (short)f2bf(u.x); a[1] = (short)f2bf(u.y);
      a[2] = (short)f2bf(u.z); a[3] = (short)f2bf(u.w);
      a[4] = (short)f2bf(v.x); a[5] = (short)f2bf(v.y);
      a[6] = (short)f2bf(v.z); a[7] = (short)f2bf(v.w);
      #pragma unroll
      for (int nf = 0; nf < 4; ++nf) {
        bf16x8 b = *(const bf16x8*)(W + (size_t)(colBase + nf * 16 + la) * din + k0 + lb * 8);
        acc[nf] = __builtin_amdgcn_mfma_f32_16x16x32_bf16(a, b, acc[nf], 0, 0, 0);
      }
    }
    if (!A2) break;
    A = A2; W = W2;
  }

  // C/D layout: col = lane&15, row = (lane>>4)*4 + reg
  #pragma unroll
  for (int nf = 0; nf < 4; ++nf) {
    int col = colBase + nf * 16 + la;
    float bv = bias ? bias[col] : 0.0f;
    #pragma unroll
    for (int i = 0; i < 4; ++i) {
      int row = rowBase + lb * 4 + i;
      if (row < Mstore) C[(size_t)row * dout + col] = acc[nf][i] + bv;
    }
  }
}

// ---------- BN stats (dim 256) ----------
__global__ void k_stats(const float* __restrict__ h, float* __restrict__ stats,
                        int rowsPerBlock) {
  int c = threadIdx.x;
  int r0 = blockIdx.x * rowsPerBlock;
  int r1 = r0 + rowsPerBlock; if (r1 > N_NODES) r1 = N_NODES;
  float s = 0.f, q = 0.f;
  for (int r = r0; r < r1; ++r) {
    float v = h[(size_t)r * 256 + c];
    s += v; q += v * v;
  }
  atomicAdd(&stats[c], s);
  atomicAdd(&stats[256 + c], q);
}

__global__ void k_bnprep(const float* __restrict__ stats, const float* __restrict__ gamma,
                         const float* __restrict__ beta, float* __restrict__ bnp) {
  int c = threadIdx.x;
  float m = stats[c] * (1.0f / N_NODES);
  float var = stats[256 + c] * (1.0f / N_NODES) - m * m;
  float rs = rsqrtf(var + BN_EPS);
  float sc = rs * gamma[c];
  bnp[c] = sc;
  bnp[256 + c] = beta[c] - m * sc;
}

__global__ void k_bnrelu(float* __restrict__ h, const float* __restrict__ bnp) {
  int t = blockIdx.x * blockDim.x + threadIdx.x;
  int i = t >> 6;
  if (i >= N_NODES) return;
  int c4 = (t & 63) * 4;
  float4* p = (float4*)(h + (size_t)i * 256 + c4);
  float4 v = *p;
  float o0 = fmaxf(v.x * bnp[c4 + 0] + bnp[256 + c4 + 0], 0.f);
  float o1 = fmaxf(v.y * bnp[c4 + 1] + bnp[256 + c4 + 1], 0.f);
  float o2 = fmaxf(v.z * bnp[c4 + 2] + bnp[256 + c4 + 2], 0.f);
  float o3 = fmaxf(v.w * bnp[c4 + 3] + bnp[256 + c4 + 3], 0.f);
  *p = make_float4(o0, o1, o2, o3);
}

extern "C" void kernel_launch(void* const* d_in, const int* in_sizes, int n_in,
                              void* d_out, int out_size, void* d_ws, size_t ws_size,
                              hipStream_t stream) {
  const float* x    = (const float*)d_in[0];
  const int*   ei   = (const int*)d_in[1];
  const float* encW = (const float*)d_in[2];
  const float* encb = (const float*)d_in[3];
  const float* Wl0  = (const float*)d_in[4];
  const float* bl0  = (const float*)d_in[5];
  const float* Wr0  = (const float*)d_in[6];
  const float* Wl1  = (const float*)d_in[7];
  const float* bl1  = (const float*)d_in[8];
  const float* Wr1  = (const float*)d_in[9];
  const float* Wl2  = (const float*)d_in[10];
  const float* bl2  = (const float*)d_in[11];
  const float* Wr2  = (const float*)d_in[12];
  const float* Wl3  = (const float*)d_in[13];
  const float* bl3  = (const float*)d_in[14];
  const float* Wr3  = (const float*)d_in[15];
  const float* g0   = (const float*)d_in[16];
  const float* b0   = (const float*)d_in[17];
  const float* g1   = (const float*)d_in[18];
  const float* b1   = (const float*)d_in[19];
  const float* g2   = (const float*)d_in[20];
  const float* b2   = (const float*)d_in[21];
  const float* decW = (const float*)d_in[22];
  const float* decb = (const float*)d_in[23];

  const int* src = ei;
  const int* dst = ei + N_EDGES;

  char* ws = (char*)d_ws;
  size_t off = 0;
  auto alloc = [&](size_t bytes) { char* p = ws + off; off += (bytes + 255) & ~255ull; return p; };
  float*  bufA   = (float*) alloc((size_t)NPAD * 256 * 4);
  float*  bufB   = (float*) alloc((size_t)NPAD * 256 * 4);
  float*  mean   = (float*) alloc((size_t)NPAD * 256 * 4);
  int*    deg    = (int*)   alloc((size_t)N_NODES * 4);
  int*    rowptr = (int*)   alloc((size_t)(N_NODES + 1) * 4);
  int*    cursor = (int*)   alloc((size_t)N_NODES * 4);
  int*    colidx = (int*)   alloc((size_t)N_EDGES * 4);
  float*  inv    = (float*) alloc((size_t)N_NODES * 4);
  float*  stats  = (float*) alloc(512 * 4);
  float*  bnp    = (float*) alloc(512 * 4);
  ushort* wpool  = (ushort*)alloc(425984 * 2);

  const ushort* wEnc = wpool;
  const ushort* wL0  = wpool + 16384;
  const ushort* wR0  = wpool + 49152;
  const ushort* wL1  = wpool + 81920;
  const ushort* wR1  = wpool + 147456;
  const ushort* wL2  = wpool + 212992;
  const ushort* wR2  = wpool + 278528;
  const ushort* wL3  = wpool + 344064;
  const ushort* wR3  = wpool + 376832;
  const ushort* wDec = wpool + 409600;

  // ---- CSR build (once; reused by all 4 layers) ----
  hipMemsetAsync(deg, 0, (size_t)N_NODES * 4, stream);
  k_deg<<<(N_EDGES + 255) / 256, 256, 0, stream>>>(dst, deg);
  k_scan<<<1, 256, 0, stream>>>(deg, rowptr, inv);
  hipMemcpyAsync(cursor, rowptr, (size_t)N_NODES * 4, hipMemcpyDeviceToDevice, stream);
  k_fill<<<(N_EDGES + 255) / 256, 256, 0, stream>>>(src, dst, cursor, colidx);

  k_cvtw<<<(106496 + 255) / 256, 256, 0, stream>>>(encW, Wl0, Wr0, Wl1, Wr1, Wl2, Wr2,
                                                   Wl3, Wr3, decW, wpool);

  // encoder: bufA = x @ encW^T + encb
  {
    dim3 grid(NPAD / 64, 2);
    k_gemm<<<grid, 256, 0, stream>>>(x, wEnc, nullptr, nullptr, encb,
                                     bufA, N_NODES, 128, 128);
  }

  auto sage = [&](const float* z, int din_, const ushort* Wlb, const float* bl,
                  const ushort* Wrb, int dout_, float* outb) {
    if (din_ == 256)
      k_gather<256><<<(N_NODES + 3) / 4, 256, 0, stream>>>(z, rowptr, colidx, inv, mean);
    else
      k_gather<128><<<(N_NODES + 3) / 4, 256, 0, stream>>>(z, rowptr, colidx, inv, mean);
    dim3 grid(NPAD / 64, dout_ / 64);
    k_gemm<<<grid, 256, 0, stream>>>(mean, Wlb, z, Wrb, bl, outb, N_NODES, din_, dout_);
  };
  auto bnrelu = [&](float* h, const float* ga, const float* be) {
    hipMemsetAsync(stats, 0, 512 * 4, stream);
    k_stats<<<200, 256, 0, stream>>>(h, stats, 100);
    k_bnprep<<<1, 256, 0, stream>>>(stats, ga, be, bnp);
    int total = N_NODES * 64;
    k_bnrelu<<<(total + 255) / 256, 256, 0, stream>>>(h, bnp);
  };

  sage(bufA, 128, wL0, bl0, wR0, 256, bufB); bnrelu(bufB, g0, b0);
  sage(bufB, 256, wL1, bl1, wR1, 256, bufA); bnrelu(bufA, g1, b1);
  sage(bufA, 256, wL2, bl2, wR2, 256, bufB); bnrelu(bufB, g2, b2);
  sage(bufB, 256, wL3, bl3, wR3, 128, bufA);   // layer 3: no BN/ReLU

  // decoder: d_out = bufA @ decW^T + decb
  {
    dim3 grid(NPAD / 64, 2);
    k_gemm<<<grid, 256, 0, stream>>>(bufA, wDec, nullptr, nullptr, decb,
                                     (float*)d_out, N_NODES, 128, 128);
  }
}

// Round 4
// 504.163 us; speedup vs baseline: 16.0327x; 1.3159x over previous
//
#include <hip/hip_runtime.h>

#define N_NODES 20000
#define N_EDGES 320000
#define NPAD    20032
#define BN_EPS  1e-5f
#define NBLK    79          // ceil(20000/256)

using bf16x8 = __attribute__((ext_vector_type(8))) short;
using f32x4  = __attribute__((ext_vector_type(4))) float;

__device__ __forceinline__ float bf2f(ushort u) {
  union { unsigned i; float f; } t; t.i = ((unsigned)u) << 16; return t.f;
}
__device__ __forceinline__ ushort f2bf(float f) {
  unsigned x = __float_as_uint(f);
  return (ushort)((x + 0x7fffu + ((x >> 16) & 1u)) >> 16);   // RNE
}

// ---------- CSR build ----------
__global__ void k_deg(const int* __restrict__ dst, int* __restrict__ deg) {
  int t = blockIdx.x * blockDim.x + threadIdx.x;
  if (t < N_EDGES) { unsigned d = (unsigned)dst[t]; if (d < N_NODES) atomicAdd(&deg[d], 1); }
}

// per-block inclusive scan of deg -> part, block totals -> bsum
__global__ void k_scanA(const int* __restrict__ deg, int* __restrict__ part,
                        int* __restrict__ bsum) {
  __shared__ int buf[256];
  int i = blockIdx.x * 256 + threadIdx.x;
  int v = (i < N_NODES) ? deg[i] : 0;
  buf[threadIdx.x] = v;
  __syncthreads();
  #pragma unroll
  for (int s = 1; s < 256; s <<= 1) {
    int t = (threadIdx.x >= s) ? buf[threadIdx.x - s] : 0;
    __syncthreads();
    buf[threadIdx.x] += t;
    __syncthreads();
  }
  if (i < N_NODES) part[i] = buf[threadIdx.x];
  if (threadIdx.x == 255) bsum[blockIdx.x] = buf[255];
}

// single block: inclusive scan of NBLK block sums in place
__global__ void k_scanB(int* __restrict__ bsum) {
  __shared__ int buf[128];
  int v = (threadIdx.x < NBLK) ? bsum[threadIdx.x] : 0;
  buf[threadIdx.x] = v;
  __syncthreads();
  #pragma unroll
  for (int s = 1; s < 128; s <<= 1) {
    int t = (threadIdx.x >= s) ? buf[threadIdx.x - s] : 0;
    __syncthreads();
    buf[threadIdx.x] += t;
    __syncthreads();
  }
  if (threadIdx.x < NBLK) bsum[threadIdx.x] = buf[threadIdx.x];
}

__global__ void k_scanC(const int* __restrict__ deg, const int* __restrict__ part,
                        const int* __restrict__ bsum, int* __restrict__ rowptr,
                        float* __restrict__ inv) {
  int i = blockIdx.x * 256 + threadIdx.x;
  if (i >= N_NODES) return;
  int off = blockIdx.x ? bsum[blockIdx.x - 1] : 0;
  rowptr[i + 1] = off + part[i];
  if (i == 0) rowptr[0] = 0;
  inv[i] = 1.0f / (float)max(deg[i], 1);
}

__global__ void k_fill(const int* __restrict__ src, const int* __restrict__ dst,
                       int* __restrict__ cursor, int* __restrict__ col) {
  int e = blockIdx.x * blockDim.x + threadIdx.x;
  if (e >= N_EDGES) return;
  unsigned d = (unsigned)dst[e];
  if (d >= N_NODES) return;
  int p = atomicAdd(&cursor[d], 1);
  col[p] = src[e];
}

// ---------- weights -> bf16 pool ----------
__global__ void k_cvtw(const float* s0, const float* s1, const float* s2,
                       const float* s3, const float* s4, const float* s5,
                       const float* s6, const float* s7, const float* s8,
                       const float* s9, ushort* __restrict__ dst) {
  int t = blockIdx.x * blockDim.x + threadIdx.x;
  int e = t * 4;
  if (e >= 425984) return;
  const float* s; int off;
  if      (e < 16384)  { s = s0; off = e; }
  else if (e < 49152)  { s = s1; off = e - 16384; }
  else if (e < 81920)  { s = s2; off = e - 49152; }
  else if (e < 147456) { s = s3; off = e - 81920; }
  else if (e < 212992) { s = s4; off = e - 147456; }
  else if (e < 278528) { s = s5; off = e - 212992; }
  else if (e < 344064) { s = s6; off = e - 278528; }
  else if (e < 376832) { s = s7; off = e - 344064; }
  else if (e < 409600) { s = s8; off = e - 376832; }
  else                 { s = s9; off = e - 409600; }
  float4 v = *(const float4*)(s + off);
  dst[e + 0] = f2bf(v.x); dst[e + 1] = f2bf(v.y);
  dst[e + 2] = f2bf(v.z); dst[e + 3] = f2bf(v.w);
}

// ---------- gather-mean (bf16 in, fp32 acc, bf16 out): one wave per node ----------
template <int DIM>
__global__ __launch_bounds__(256) void k_gather(
    const ushort* __restrict__ z, const int* __restrict__ rowptr,
    const int* __restrict__ col, const float* __restrict__ inv,
    ushort* __restrict__ mean) {
  int node = blockIdx.x * 4 + (threadIdx.x >> 6);
  if (node >= N_NODES) return;
  int lane = threadIdx.x & 63;
  constexpr int V = DIM / 64;                       // 4 (dim 256) or 2 (dim 128)
  float acc[V] = {};
  int r0 = rowptr[node], r1 = rowptr[node + 1];
  for (int j = r0; j < r1; ++j) {
    int s = col[j];
    const ushort* zp = z + (size_t)s * DIM + lane * V;
    if constexpr (V == 4) {
      ushort4 v = *(const ushort4*)zp;
      acc[0] += bf2f(v.x); acc[1] += bf2f(v.y);
      acc[2] += bf2f(v.z); acc[3] += bf2f(v.w);
    } else {
      ushort2 v = *(const ushort2*)zp;
      acc[0] += bf2f(v.x); acc[1] += bf2f(v.y);
    }
  }
  float iv = inv[node];
  ushort* mp = mean + (size_t)node * DIM + lane * V;
  #pragma unroll
  for (int k = 0; k < V; ++k) mp[k] = f2bf(acc[k] * iv);
}

// ---------- dual GEMM: C = A1@W1^T (+ A2@W2^T) + bias ----------
// AF32: A is f32 (converted in-reg); else A is bf16. CF32: C stored f32 else bf16.
template <bool AF32, bool CF32>
__global__ __launch_bounds__(256) void k_gemm(
    const void* __restrict__ A1v, const ushort* __restrict__ W1,
    const void* __restrict__ A2v, const ushort* __restrict__ W2,
    const float* __restrict__ bias, void* __restrict__ Cv,
    int Mstore, int din, int dout)
{
  int lane = threadIdx.x & 63, wid = threadIdx.x >> 6;
  int la = lane & 15, lb = lane >> 4;
  int rowBase = blockIdx.x * 64 + wid * 16;
  int colBase = blockIdx.y * 64;
  int arow = rowBase + la; if (arow >= N_NODES) arow = N_NODES - 1;

  f32x4 acc[4] = {{0,0,0,0},{0,0,0,0},{0,0,0,0},{0,0,0,0}};

  const void* A = A1v; const ushort* W = W1;
  #pragma unroll 1
  for (int pass = 0; pass < 2; ++pass) {
    for (int k0 = 0; k0 < din; k0 += 32) {
      bf16x8 a;
      if constexpr (AF32) {
        const float* ap = (const float*)A + (size_t)arow * din + lb * 8 + k0;
        float4 u = *(const float4*)ap;
        float4 v = *(const float4*)(ap + 4);
        a[0] = (short)f2bf(u.x); a[1] = (short)f2bf(u.y);
        a[2] = (short)f2bf(u.z); a[3] = (short)f2bf(u.w);
        a[4] = (short)f2bf(v.x); a[5] = (short)f2bf(v.y);
        a[6] = (short)f2bf(v.z); a[7] = (short)f2bf(v.w);
      } else {
        a = *(const bf16x8*)((const ushort*)A + (size_t)arow * din + lb * 8 + k0);
      }
      #pragma unroll
      for (int nf = 0; nf < 4; ++nf) {
        bf16x8 b = *(const bf16x8*)(W + (size_t)(colBase + nf * 16 + la) * din + k0 + lb * 8);
        acc[nf] = __builtin_amdgcn_mfma_f32_16x16x32_bf16(a, b, acc[nf], 0, 0, 0);
      }
    }
    if (!A2v) break;
    A = A2v; W = W2;
  }

  // C/D layout: col = lane&15, row = (lane>>4)*4 + reg
  #pragma unroll
  for (int nf = 0; nf < 4; ++nf) {
    int col = colBase + nf * 16 + la;
    float bv = bias ? bias[col] : 0.0f;
    #pragma unroll
    for (int i = 0; i < 4; ++i) {
      int row = rowBase + lb * 4 + i;
      if (row < Mstore) {
        float o = acc[nf][i] + bv;
        if constexpr (CF32) ((float*)Cv)[(size_t)row * dout + col] = o;
        else                ((ushort*)Cv)[(size_t)row * dout + col] = f2bf(o);
      }
    }
  }
}

// ---------- BN stats (dim 256, bf16 input) ----------
__global__ void k_stats(const ushort* __restrict__ h, float* __restrict__ stats,
                        int rowsPerBlock) {
  int c = threadIdx.x;
  int r0 = blockIdx.x * rowsPerBlock;
  int r1 = r0 + rowsPerBlock; if (r1 > N_NODES) r1 = N_NODES;
  float s = 0.f, q = 0.f;
  for (int r = r0; r < r1; ++r) {
    float v = bf2f(h[(size_t)r * 256 + c]);
    s += v; q += v * v;
  }
  atomicAdd(&stats[c], s);
  atomicAdd(&stats[256 + c], q);
}

__global__ void k_bnprep(const float* __restrict__ stats, const float* __restrict__ gamma,
                         const float* __restrict__ beta, float* __restrict__ bnp) {
  int c = threadIdx.x;
  float m = stats[c] * (1.0f / N_NODES);
  float var = stats[256 + c] * (1.0f / N_NODES) - m * m;
  float rs = rsqrtf(var + BN_EPS);
  float sc = rs * gamma[c];
  bnp[c] = sc;
  bnp[256 + c] = beta[c] - m * sc;
}

// BN apply + ReLU in place (bf16, dim 256), 8 elems/thread
__global__ void k_bnrelu(ushort* __restrict__ h, const float* __restrict__ bnp) {
  int t = blockIdx.x * blockDim.x + threadIdx.x;
  int i = t >> 5;
  if (i >= N_NODES) return;
  int g = t & 31;
  ushort* p = h + (size_t)i * 256 + g * 8;
  bf16x8 v = *(bf16x8*)p;
  #pragma unroll
  for (int j = 0; j < 8; ++j) {
    int c = g * 8 + j;
    float f = bf2f((ushort)v[j]) * bnp[c] + bnp[256 + c];
    v[j] = (short)f2bf(fmaxf(f, 0.0f));
  }
  *(bf16x8*)p = v;
}

extern "C" void kernel_launch(void* const* d_in, const int* in_sizes, int n_in,
                              void* d_out, int out_size, void* d_ws, size_t ws_size,
                              hipStream_t stream) {
  const float* x    = (const float*)d_in[0];
  const int*   ei   = (const int*)d_in[1];
  const float* encW = (const float*)d_in[2];
  const float* encb = (const float*)d_in[3];
  const float* Wl0  = (const float*)d_in[4];
  const float* bl0  = (const float*)d_in[5];
  const float* Wr0  = (const float*)d_in[6];
  const float* Wl1  = (const float*)d_in[7];
  const float* bl1  = (const float*)d_in[8];
  const float* Wr1  = (const float*)d_in[9];
  const float* Wl2  = (const float*)d_in[10];
  const float* bl2  = (const float*)d_in[11];
  const float* Wr2  = (const float*)d_in[12];
  const float* Wl3  = (const float*)d_in[13];
  const float* bl3  = (const float*)d_in[14];
  const float* Wr3  = (const float*)d_in[15];
  const float* g0   = (const float*)d_in[16];
  const float* b0   = (const float*)d_in[17];
  const float* g1   = (const float*)d_in[18];
  const float* b1   = (const float*)d_in[19];
  const float* g2   = (const float*)d_in[20];
  const float* b2   = (const float*)d_in[21];
  const float* decW = (const float*)d_in[22];
  const float* decb = (const float*)d_in[23];

  const int* src = ei;
  const int* dst = ei + N_EDGES;

  char* ws = (char*)d_ws;
  size_t off = 0;
  auto alloc = [&](size_t bytes) { char* p = ws + off; off += (bytes + 255) & ~255ull; return p; };
  ushort* bufA   = (ushort*)alloc((size_t)NPAD * 256 * 2);
  ushort* bufB   = (ushort*)alloc((size_t)NPAD * 256 * 2);
  ushort* mean   = (ushort*)alloc((size_t)NPAD * 256 * 2);
  int*    deg    = (int*)   alloc((size_t)N_NODES * 4);
  int*    part   = (int*)   alloc((size_t)N_NODES * 4);
  int*    bsum   = (int*)   alloc(128 * 4);
  int*    rowptr = (int*)   alloc((size_t)(N_NODES + 1) * 4);
  int*    cursor = (int*)   alloc((size_t)N_NODES * 4);
  int*    colidx = (int*)   alloc((size_t)N_EDGES * 4);
  float*  inv    = (float*) alloc((size_t)N_NODES * 4);
  float*  stats  = (float*) alloc(512 * 4);
  float*  bnp    = (float*) alloc(512 * 4);
  ushort* wpool  = (ushort*)alloc(425984 * 2);

  const ushort* wEnc = wpool;
  const ushort* wL0  = wpool + 16384;
  const ushort* wR0  = wpool + 49152;
  const ushort* wL1  = wpool + 81920;
  const ushort* wR1  = wpool + 147456;
  const ushort* wL2  = wpool + 212992;
  const ushort* wR2  = wpool + 278528;
  const ushort* wL3  = wpool + 344064;
  const ushort* wR3  = wpool + 376832;
  const ushort* wDec = wpool + 409600;

  // ---- CSR build (once; reused by all 4 layers) ----
  hipMemsetAsync(deg, 0, (size_t)N_NODES * 4, stream);
  k_deg<<<(N_EDGES + 255) / 256, 256, 0, stream>>>(dst, deg);
  k_scanA<<<NBLK, 256, 0, stream>>>(deg, part, bsum);
  k_scanB<<<1, 128, 0, stream>>>(bsum);
  k_scanC<<<NBLK, 256, 0, stream>>>(deg, part, bsum, rowptr, inv);
  hipMemcpyAsync(cursor, rowptr, (size_t)N_NODES * 4, hipMemcpyDeviceToDevice, stream);
  k_fill<<<(N_EDGES + 255) / 256, 256, 0, stream>>>(src, dst, cursor, colidx);

  k_cvtw<<<(106496 + 255) / 256, 256, 0, stream>>>(encW, Wl0, Wr0, Wl1, Wr1, Wl2, Wr2,
                                                   Wl3, Wr3, decW, wpool);

  // encoder: bufA = x @ encW^T + encb  (f32 A, bf16 C)
  {
    dim3 grid(NPAD / 64, 2);
    k_gemm<true, false><<<grid, 256, 0, stream>>>(x, wEnc, nullptr, nullptr, encb,
                                                  bufA, N_NODES, 128, 128);
  }

  auto sage = [&](const ushort* z, int din_, const ushort* Wlb, const float* bl,
                  const ushort* Wrb, int dout_, ushort* outb) {
    if (din_ == 256)
      k_gather<256><<<(N_NODES + 3) / 4, 256, 0, stream>>>(z, rowptr, colidx, inv, mean);
    else
      k_gather<128><<<(N_NODES + 3) / 4, 256, 0, stream>>>(z, rowptr, colidx, inv, mean);
    dim3 grid(NPAD / 64, dout_ / 64);
    k_gemm<false, false><<<grid, 256, 0, stream>>>(mean, Wlb, z, Wrb, bl,
                                                   outb, N_NODES, din_, dout_);
  };
  auto bnrelu = [&](ushort* h, const float* ga, const float* be) {
    hipMemsetAsync(stats, 0, 512 * 4, stream);
    k_stats<<<200, 256, 0, stream>>>(h, stats, 100);
    k_bnprep<<<1, 256, 0, stream>>>(stats, ga, be, bnp);
    int total = N_NODES * 32;
    k_bnrelu<<<(total + 255) / 256, 256, 0, stream>>>(h, bnp);
  };

  sage(bufA, 128, wL0, bl0, wR0, 256, bufB); bnrelu(bufB, g0, b0);
  sage(bufB, 256, wL1, bl1, wR1, 256, bufA); bnrelu(bufA, g1, b1);
  sage(bufA, 256, wL2, bl2, wR2, 256, bufB); bnrelu(bufB, g2, b2);
  sage(bufB, 256, wL3, bl3, wR3, 128, bufA);   // layer 3: no BN/ReLU

  // decoder: d_out = bufA @ decW^T + decb  (bf16 A, f32 C)
  {
    dim3 grid(NPAD / 64, 2);
    k_gemm<false, true><<<grid, 256, 0, stream>>>(bufA, wDec, nullptr, nullptr, decb,
                                                  (float*)d_out, N_NODES, 128, 128);
  }
}